// Round 1
// baseline (347.335 us; speedup 1.0000x reference)
//
#include <hip/hip_runtime.h>
#include <hip/hip_bf16.h>

typedef __attribute__((ext_vector_type(8))) short short8;
typedef __attribute__((ext_vector_type(4))) short short4v;
typedef __attribute__((ext_vector_type(4))) float float4v;

static __device__ __forceinline__ float b2f(short s) {
    return __builtin_bit_cast(float, ((unsigned)(unsigned short)s) << 16);
}
// fp32 -> bf16 round-to-nearest-even (finite values only)
static __device__ __forceinline__ short f2b(float f) {
    unsigned x = __builtin_bit_cast(unsigned, f);
    unsigned r = (x + 0x7fffu + ((x >> 16) & 1u)) >> 16;
    return (short)r;
}
// async global->LDS, 16B per lane (dst must be wave-uniform base + lane*16)
static __device__ __forceinline__ void gload_lds16(const short* g, short* l) {
    __builtin_amdgcn_global_load_lds(
        (const __attribute__((address_space(1))) void*)g,
        (__attribute__((address_space(3))) void*)l, 16, 0, 0);
}

// ------------- prep: fp32->bf16 convert of x + all 6 weight transposes ---------
static __device__ __forceinline__ void tile_transpose(const float* __restrict__ in,
                                                      short* __restrict__ out,
                                                      int R, int C, int bx, int by,
                                                      float tile[64][65])
{
    const int tx = threadIdx.x;
    const int r0 = by * 64, c0 = bx * 64;
    const int lr = tx >> 4, lc = (tx & 15) * 4;
#pragma unroll
    for (int p = 0; p < 4; p++) {
        const float4v v = *(const float4v*)&in[(size_t)(r0 + lr + p * 16) * C + c0 + lc];
#pragma unroll
        for (int j = 0; j < 4; j++) tile[lr + p * 16][lc + j] = v[j];
    }
    __syncthreads();
    const int oc = tx >> 3, orr = (tx & 7) * 8;
#pragma unroll
    for (int p = 0; p < 2; p++) {
        const int c = oc + p * 32;
        short8 pk;
#pragma unroll
        for (int j = 0; j < 8; j++) pk[j] = f2b(tile[orr + j][c]);
        *(short8*)&out[(size_t)(c0 + c) * R + r0 + orr] = pk;
    }
}

__global__ __launch_bounds__(256) void prep_k(const float* __restrict__ x,
                                              const float* __restrict__ Wq,
                                              const float* __restrict__ Wk,
                                              const float* __restrict__ Wv,
                                              const float* __restrict__ Wp,
                                              const float* __restrict__ W1,
                                              const float* __restrict__ W2,
                                              short* __restrict__ xb,
                                              short* __restrict__ WqkvT,
                                              short* __restrict__ WpT,
                                              short* __restrict__ W1T,
                                              short* __restrict__ W2T)
{
    __shared__ float tile[64][65];
    const int b = blockIdx.x;
    if (b < 4096) {
        const size_t i = ((size_t)b * 256 + threadIdx.x) * 4;
        const float4v v = *(const float4v*)&x[i];
        short4v s;
#pragma unroll
        for (int j = 0; j < 4; j++) s[j] = f2b(v[j]);
        *(short4v*)&xb[i] = s;
    } else if (b < 5120) {
        const int lb = b - 4096;
        const int wsel = lb >> 8, t = lb & 255;
        const float* in = (wsel == 0) ? Wq : (wsel == 1) ? Wk : (wsel == 2) ? Wv : Wp;
        short* out = (wsel < 3) ? (WqkvT + ((size_t)wsel << 20)) : WpT;
        tile_transpose(in, out, 1024, 1024, t & 15, t >> 4, tile);
    } else if (b < 6144) {
        const int lb = b - 5120;
        tile_transpose(W1, W1T, 1024, 4096, lb & 63, lb >> 6, tile);
    } else {
        const int lb = b - 6144;
        tile_transpose(W2, W2T, 4096, 1024, lb & 15, lb >> 4, tile);
    }
}

// ---------------- 8-phase 256x256 GEMM: C[M,N] = X[M,K] @ Wt[N,K]^T -----------
// 512 threads / 8 waves (2M x 4N), BK=64, double-buffered 128 KiB LDS.
// LDS layout per matrix: [buf][khalf][256 rows][32 cols] bf16, rows XOR-swizzled
// (byte ^= (row&3)<<4) via pre-swizzled global_load_lds source addresses.
// Phase order per K-tile: (k0,mh0)(k0,mh1)(k1,mh1)(k1,mh0); tile t+1's four
// regions (A.k0,B.k0,A.k1,B.k1) staged one per phase into buf[(t+1)&1];
// s_waitcnt vmcnt(4) at end of phases 1 and 3 (counted, never 0 in loop).
// MODE 2: out = relu(v + bias[n]) bf16. MODE 4: fused QKV scatter (Q*0.125,
// K, V^T segments 4M elems apart). MODE 5: split-K over blockIdx.z, bf16
// partials at out + z*M*N (z==3 redirected to 'alt' when non-null).
template<int MODE>
__global__ __launch_bounds__(512, 2) void gemm8(const short* __restrict__ X,
                                                const short* __restrict__ Wt,
                                                short* __restrict__ out,
                                                const float* __restrict__ bias,
                                                const short* __restrict__ alt,
                                                int M, int N, int K)
{
    extern __shared__ char lds[];
    const int tid = threadIdx.x;
    const int wave = tid >> 6, lane = tid & 63;
    const int quad = lane >> 4, l16 = lane & 15;
    const int wm = (wave >> 2) * 128, wn = (wave & 3) * 64;

    int bx = blockIdx.x, by = blockIdx.y;
    {   // XCD-aware bijective swizzle (perf heuristic only)
        const int nbx = gridDim.x, nby = gridDim.y;
        if ((nby & 7) == 0) {
            const int g = by * nbx + bx;
            const int xcd = g & 7, loc = g >> 3, Y = nby >> 3;
            by = xcd * Y + (loc % Y);
            bx = loc / Y;
        }
    }
    const int m0 = by * 256, n0 = bx * 256;

    int nt = K >> 6, kb = 0;
    if (MODE == 5) { nt /= (int)gridDim.z; kb = blockIdx.z * nt; }

    // staging geometry: thread covers (row = tid>>2 [+128], 16B granule tid&3)
    const int sr = tid >> 2;
    const int ce = ((((tid & 3) << 4) ^ ((sr & 3) << 4)) >> 1);  // swizzled col (elems)
    const int sx = (l16 & 3) << 4;                               // read-side XOR (bytes)

    auto stage = [&](int t, int isB, int kh) {
        const short* src = isB ? Wt : X;
        const int rb = isB ? n0 : m0;
        const short* g = src + (size_t)(rb + sr) * K + (size_t)(kb + t) * 64 + kh * 32 + ce;
        short* d = (short*)(lds + (isB ? 65536 : 0) + ((t & 1) << 15) + (kh << 14)) + tid * 8;
        gload_lds16(g, d);
        gload_lds16(g + (size_t)128 * K, d + 4096);
    };

    float4v acc[8][4] = {};
    short8 af[4], bf[4];

    auto loadA = [&](int t, int kh, int h) {
#pragma unroll
        for (int i = 0; i < 4; i++) {
            const int row = wm + h * 64 + i * 16 + l16;
            af[i] = *(const short8*)(lds + ((t & 1) << 15) + (kh << 14) + row * 64 + ((quad << 4) ^ sx));
        }
    };
    auto loadB = [&](int t, int kh) {
#pragma unroll
        for (int i = 0; i < 4; i++) {
            const int row = wn + i * 16 + l16;
            bf[i] = *(const short8*)(lds + 65536 + ((t & 1) << 15) + (kh << 14) + row * 64 + ((quad << 4) ^ sx));
        }
    };
    auto mmac = [&](int h) {
#pragma unroll
        for (int mi = 0; mi < 4; mi++)
#pragma unroll
            for (int ni = 0; ni < 4; ni++)
                acc[h * 4 + mi][ni] = __builtin_amdgcn_mfma_f32_16x16x32_bf16(af[mi], bf[ni], acc[h * 4 + mi][ni], 0, 0, 0);
    };

    // prologue: stage tile 0 fully; k0 must land, k1 pair (4 loads) may fly
    stage(0, 0, 0); stage(0, 1, 0); stage(0, 0, 1); stage(0, 1, 1);
    asm volatile("s_waitcnt vmcnt(4)" ::: "memory");
    __builtin_amdgcn_s_barrier();

    for (int t = 0; t < nt - 1; ++t) {
        // phase 0: (k0, mh0); stage (t+1).A.k0
        loadA(t, 0, 0); loadB(t, 0);
        stage(t + 1, 0, 0);
        __builtin_amdgcn_s_barrier();
        asm volatile("s_waitcnt lgkmcnt(0)" ::: "memory");
        __builtin_amdgcn_sched_barrier(0);
        __builtin_amdgcn_s_setprio(1); mmac(0); __builtin_amdgcn_s_setprio(0);
        __builtin_amdgcn_s_barrier();
        // phase 1: (k0, mh1); stage (t+1).B.k0; vmcnt(4) -> tile t k1 landed
        loadA(t, 0, 1);
        stage(t + 1, 1, 0);
        __builtin_amdgcn_s_barrier();
        asm volatile("s_waitcnt lgkmcnt(0)" ::: "memory");
        __builtin_amdgcn_sched_barrier(0);
        __builtin_amdgcn_s_setprio(1); mmac(1); __builtin_amdgcn_s_setprio(0);
        asm volatile("s_waitcnt vmcnt(4)" ::: "memory");
        __builtin_amdgcn_s_barrier();
        // phase 2: (k1, mh1); stage (t+1).A.k1
        loadA(t, 1, 1); loadB(t, 1);
        stage(t + 1, 0, 1);
        __builtin_amdgcn_s_barrier();
        asm volatile("s_waitcnt lgkmcnt(0)" ::: "memory");
        __builtin_amdgcn_sched_barrier(0);
        __builtin_amdgcn_s_setprio(1); mmac(1); __builtin_amdgcn_s_setprio(0);
        __builtin_amdgcn_s_barrier();
        // phase 3: (k1, mh0); stage (t+1).B.k1; vmcnt(4) -> tile t+1 k0 landed
        loadA(t, 1, 0);
        stage(t + 1, 1, 1);
        __builtin_amdgcn_s_barrier();
        asm volatile("s_waitcnt lgkmcnt(0)" ::: "memory");
        __builtin_amdgcn_sched_barrier(0);
        __builtin_amdgcn_s_setprio(1); mmac(0); __builtin_amdgcn_s_setprio(0);
        asm volatile("s_waitcnt vmcnt(4)" ::: "memory");
        __builtin_amdgcn_s_barrier();
    }
    // epilogue tile (no staging; only cross-wave hazard is the k1 landing)
    {
        const int t = nt - 1;
        loadA(t, 0, 0); loadB(t, 0);
        mmac(0);
        loadA(t, 0, 1);
        mmac(1);
        asm volatile("s_waitcnt vmcnt(0)" ::: "memory");
        __builtin_amdgcn_s_barrier();
        loadA(t, 1, 1); loadB(t, 1);
        mmac(1);
        loadA(t, 1, 0);
        mmac(0);
    }

    short* op = out;
    if (MODE == 5) op = (blockIdx.z == 3 && alt) ? const_cast<short*>(alt)
                                                 : out + (size_t)blockIdx.z * M * N;

#pragma unroll
    for (int mf = 0; mf < 8; mf++) {
#pragma unroll
        for (int nf = 0; nf < 4; nf++) {
            const int gn = n0 + wn + nf * 16 + l16;
            const float bv = (MODE == 2) ? bias[gn] : 0.0f;
#pragma unroll
            for (int rr = 0; rr < 4; rr++) {
                const int gm = m0 + wm + mf * 16 + (quad << 2) + rr;
                float v = acc[mf][nf][rr];
                if (MODE == 4) {
                    const int s = gn >> 10;          // block-uniform
                    const int n = gn & 1023;
                    const int hh = n >> 6, d = n & 63;
                    const size_t bh16 = (size_t)((gm >> 10) * 16 + hh) << 16;
                    const size_t base = (size_t)s << 22;
                    if (s == 0)      out[base + bh16 + ((size_t)(gm & 1023) << 6) + d] = f2b(v * 0.125f);
                    else if (s == 1) out[base + bh16 + ((size_t)(gm & 1023) << 6) + d] = f2b(v);
                    else             out[base + bh16 + ((size_t)d << 10) + (gm & 1023)] = f2b(v);
                } else if (MODE == 2) {
                    v = fmaxf(v + bv, 0.0f);
                    out[(size_t)gm * N + gn] = f2b(v);
                } else {   // MODE 5
                    op[(size_t)gm * N + gn] = f2b(v);
                }
            }
        }
    }
}

// ---------------- attention v4: LDS-staged, no-rescale softmax -----------------
__global__ __launch_bounds__(256) void attn_k(const short* __restrict__ Qb,
                                              const short* __restrict__ Kb,
                                              const short* __restrict__ Vt,
                                              const int* __restrict__ mask,
                                              short* __restrict__ heads)
{
    __shared__ short Kl[2][64 * 32];
    __shared__ short Vl[2][64 * 32];
    __shared__ short P[4][16 * 72];
    const int bh = blockIdx.x, qb = blockIdx.y;
    const int b = bh >> 4, h = bh & 15;
    const int tid = threadIdx.x, wave = tid >> 6, lane = tid & 63;
    const int quad = lane >> 4, l16 = lane & 15;
    const int qbase = qb * 64 + wave * 16;
    const short* Qp = Qb + ((size_t)bh << 16) + (size_t)qbase * 64;
    const short* Kp = Kb + ((size_t)bh << 16);
    const short* Vp = Vt + ((size_t)bh << 16);
    const int* mp = mask + (b << 10);

    const short8 bq0 = *(const short8*)&Qp[l16 * 64 + quad * 8];
    const short8 bq1 = *(const short8*)&Qp[l16 * 64 + 32 + quad * 8];

    float rs = 0.0f;
    float4v o[4] = {};
    short* myP = &P[wave][0];

    const int srow = tid >> 2, sc8 = (tid & 3) * 8;

    for (int kc = 0; kc < 1024; kc += 64) {
        gload_lds16(Kp + (size_t)(kc + srow) * 64 + sc8,      &Kl[0][tid * 8]);
        gload_lds16(Kp + (size_t)(kc + srow) * 64 + 32 + sc8, &Kl[1][tid * 8]);
        gload_lds16(Vp + (size_t)srow * 1024 + kc + sc8,      &Vl[0][tid * 8]);
        gload_lds16(Vp + (size_t)srow * 1024 + kc + 32 + sc8, &Vl[1][tid * 8]);
        __syncthreads();

        float4v s[4];
#pragma unroll
        for (int kt = 0; kt < 4; kt++) {
            s[kt] = (float4v){};
            const short8 ka = *(const short8*)&Kl[0][(kt * 16 + l16) * 32 + quad * 8];
            s[kt] = __builtin_amdgcn_mfma_f32_16x16x32_bf16(ka, bq0, s[kt], 0, 0, 0);
            const short8 kb = *(const short8*)&Kl[1][(kt * 16 + l16) * 32 + quad * 8];
            s[kt] = __builtin_amdgcn_mfma_f32_16x16x32_bf16(kb, bq1, s[kt], 0, 0, 0);
        }
#pragma unroll
        for (int kt = 0; kt < 4; kt++) {
            const int4 mv = *(const int4*)&mp[kc + kt * 16 + quad * 4];
            float p0 = mv.x ? __expf(fminf(s[kt][0], 30.f)) : 0.f;
            float p1 = mv.y ? __expf(fminf(s[kt][1], 30.f)) : 0.f;
            float p2 = mv.z ? __expf(fminf(s[kt][2], 30.f)) : 0.f;
            float p3 = mv.w ? __expf(fminf(s[kt][3], 30.f)) : 0.f;
            rs += (p0 + p1) + (p2 + p3);
            short4v w;
            w[0] = f2b(p0); w[1] = f2b(p1); w[2] = f2b(p2); w[3] = f2b(p3);
            *(short4v*)&myP[l16 * 72 + kt * 16 + quad * 4] = w;
        }
        const short8 bp0 = *(const short8*)&myP[l16 * 72 + quad * 8];
        const short8 bp1 = *(const short8*)&myP[l16 * 72 + 32 + quad * 8];
#pragma unroll
        for (int dt = 0; dt < 4; dt++) {
            const short8 va = *(const short8*)&Vl[0][(dt * 16 + l16) * 32 + quad * 8];
            o[dt] = __builtin_amdgcn_mfma_f32_16x16x32_bf16(va, bp0, o[dt], 0, 0, 0);
            const short8 vb = *(const short8*)&Vl[1][(dt * 16 + l16) * 32 + quad * 8];
            o[dt] = __builtin_amdgcn_mfma_f32_16x16x32_bf16(vb, bp1, o[dt], 0, 0, 0);
        }
        __syncthreads();
    }

    rs += __shfl_xor(rs, 16);
    rs += __shfl_xor(rs, 32);
    const float inv = 1.0f / fmaxf(rs, 1e-20f);
    const int gq = qbase + l16;
#pragma unroll
    for (int dt = 0; dt < 4; dt++) {
        short4v w;
#pragma unroll
        for (int r = 0; r < 4; r++) w[r] = f2b(o[dt][r] * inv);
        *(short4v*)&heads[((size_t)(b * 1024 + gq) << 10) + h * 64 + dt * 16 + quad * 4] = w;
    }
}

// ------- fused split-K(4) reduce + LayerNorm: y = p0+p1+p2+p3+bias+res --------
template<bool F32OUT>
__global__ __launch_bounds__(256) void red_ln_k(const short* __restrict__ p0,
                                                const short* __restrict__ p1,
                                                const short* __restrict__ p2,
                                                const short* __restrict__ p3,
                                                const float* __restrict__ bias,
                                                const short* __restrict__ res,
                                                const float* __restrict__ g,
                                                const float* __restrict__ be,
                                                short* __restrict__ outb,
                                                float* __restrict__ outf)
{
    __shared__ float red[8];
    const int row = blockIdx.x, tid = threadIdx.x;
    const size_t base = ((size_t)row << 10) + tid * 4;
    const short4v a = *(const short4v*)&p0[base];
    const short4v b = *(const short4v*)&p1[base];
    const short4v c = *(const short4v*)&p2[base];
    const short4v d = *(const short4v*)&p3[base];
    const short4v e = *(const short4v*)&res[base];
    const float4v bv = *(const float4v*)&bias[tid * 4];
    float v[4];
#pragma unroll
    for (int i = 0; i < 4; i++)
        v[i] = (b2f(a[i]) + b2f(b[i])) + (b2f(c[i]) + b2f(d[i])) + bv[i] + b2f(e[i]);
    float s = v[0] + v[1] + v[2] + v[3];
#pragma unroll
    for (int off = 32; off; off >>= 1) s += __shfl_xor(s, off);
    if ((tid & 63) == 0) red[tid >> 6] = s;
    __syncthreads();
    const float mu = (red[0] + red[1] + red[2] + red[3]) * (1.0f / 1024.0f);
    float vs = 0.f;
#pragma unroll
    for (int i = 0; i < 4; i++) { const float dd = v[i] - mu; vs += dd * dd; }
#pragma unroll
    for (int off = 32; off; off >>= 1) vs += __shfl_xor(vs, off);
    if ((tid & 63) == 0) red[4 + (tid >> 6)] = vs;
    __syncthreads();
    const float rstd = rsqrtf((red[4] + red[5] + red[6] + red[7]) * (1.0f / 1024.0f) + 1e-5f);
    const float4v gv = *(const float4v*)&g[tid * 4];
    const float4v bev = *(const float4v*)&be[tid * 4];
    if (F32OUT) {
        float4v w;
#pragma unroll
        for (int i = 0; i < 4; i++) w[i] = (v[i] - mu) * rstd * gv[i] + bev[i];
        *(float4v*)&outf[base] = w;
    } else {
        short4v w;
#pragma unroll
        for (int i = 0; i < 4; i++) w[i] = f2b((v[i] - mu) * rstd * gv[i] + bev[i]);
        *(short4v*)&outb[base] = w;
    }
}

extern "C" void kernel_launch(void* const* d_in, const int* in_sizes, int n_in,
                              void* d_out, int out_size, void* d_ws, size_t ws_size,
                              hipStream_t stream)
{
    const float* x   = (const float*)d_in[0];
    const int*   mk  = (const int*)d_in[1];
    const float* Wq  = (const float*)d_in[2];
    const float* Wk  = (const float*)d_in[3];
    const float* Wv  = (const float*)d_in[4];
    const float* Wp  = (const float*)d_in[5];
    const float* bp  = (const float*)d_in[6];
    const float* W1  = (const float*)d_in[7];
    const float* b1  = (const float*)d_in[8];
    const float* W2  = (const float*)d_in[9];
    const float* b2  = (const float*)d_in[10];
    const float* g1  = (const float*)d_in[11];
    const float* be1 = (const float*)d_in[12];
    const float* g2  = (const float*)d_in[13];
    const float* be2 = (const float*)d_in[14];
    float* out = (float*)d_out;

    char* ws = (char*)d_ws;
    const size_t MB = (size_t)1 << 20;
    // liveness-packed 80 MB workspace:
    short* xb     = (short*)(ws + 0 * MB);   // 8 MB   (steps 0->4, residual 1)
    short* WqkvT  = (short*)(ws + 8 * MB);   // 6 MB   (0->1)
    short* WpT    = (short*)(ws + 14 * MB);  // 2 MB   (0->3)
    short* W1T    = (short*)(ws + 16 * MB);  // 8 MB   (0->5)
    short* partP  = (short*)(ws + 24 * MB);  // 32 MB  (3->4) proj partials, 4 slices
    short* u      = (short*)(ws + 24 * MB);  // 32 MB  (5->6) FF1 out (over partP)
    short* Qb     = (short*)(ws + 32 * MB);  // 8+8+8  (1->2) Q,K,V segments
    short* hd     = (short*)(ws + 56 * MB);  // 8 MB   (2->3) heads
    short* hbuf   = (short*)(ws + 64 * MB);  // 8 MB   (4->7) LN1 out (residual 2)
    short* W2T    = (short*)(ws + 72 * MB);  // 8 MB   (0->6)
    short* partF  = (short*)(ws + 0 * MB);   // slices 0,1,2 @ 0,8,16 MB (6->7)
    short* partF3 = (short*)(ws + 56 * MB);  // slice 3 over dead hd

    // opt-in to 128 KiB dynamic LDS for the 8-phase GEMM (host-side, capture-safe)
    hipFuncSetAttribute(reinterpret_cast<const void*>(gemm8<4>),
                        hipFuncAttributeMaxDynamicSharedMemorySize, 131072);
    hipFuncSetAttribute(reinterpret_cast<const void*>(gemm8<2>),
                        hipFuncAttributeMaxDynamicSharedMemorySize, 131072);
    hipFuncSetAttribute(reinterpret_cast<const void*>(gemm8<5>),
                        hipFuncAttributeMaxDynamicSharedMemorySize, 131072);

    const dim3 blk(256), blk8(512);

    // 0) prep: cvt(x) + 6 weight transposes in one launch
    prep_k<<<dim3(7168), blk, 0, stream>>>(x, Wq, Wk, Wv, Wp, W1, W2,
                                           xb, WqkvT, WpT, W1T, W2T);

    // 1) fused QKV: M=4096, N=3072, K=1024 -> 192 blocks (256^2 tiles)
    gemm8<4><<<dim3(12, 16), blk8, 131072, stream>>>(xb, WqkvT, Qb, nullptr, nullptr, 4096, 3072, 1024);

    // 2) attention -> heads
    attn_k<<<dim3(64, 16), blk, 0, stream>>>(Qb, Qb + (4u << 20), Qb + (8u << 20), mk, hd);

    // 3) out-proj split-K=4: 64 tiles x 4 slices = 256 blocks, K=256 each
    gemm8<5><<<dim3(4, 16, 4), blk8, 131072, stream>>>(hd, WpT, partP, nullptr, nullptr, 4096, 1024, 1024);

    // 4) reduce(4) + bias + residual(xb) + LN1 -> hbuf
    red_ln_k<false><<<dim3(4096), blk, 0, stream>>>(partP, partP + (4u << 20), partP + (8u << 20), partP + (12u << 20),
                                                    bp, xb, g1, be1, hbuf, nullptr);

    // 5) FF1 + bias + relu: 256 blocks (1/CU)
    gemm8<2><<<dim3(16, 16), blk8, 131072, stream>>>(hbuf, W1T, u, b1, nullptr, 4096, 4096, 1024);

    // 6) FF2 split-K=4: 64 tiles x 4 = 256 blocks, K=1024 each; slice 3 -> partF3
    gemm8<5><<<dim3(4, 16, 4), blk8, 131072, stream>>>(u, W2T, partF, nullptr, partF3, 4096, 1024, 4096);

    // 7) reduce(4) + bias + residual(hbuf) + LN2 -> out (fp32)
    red_ln_k<true><<<dim3(4096), blk, 0, stream>>>(partF, partF + (4u << 20), partF + (8u << 20), partF3,
                                                   b2, hbuf, g2, be2, nullptr, out);
}

// Round 2
// 342.187 us; speedup vs baseline: 1.0150x; 1.0150x over previous
//
#include <hip/hip_runtime.h>
#include <hip/hip_bf16.h>

typedef __attribute__((ext_vector_type(8))) short short8;
typedef __attribute__((ext_vector_type(4))) short short4v;
typedef __attribute__((ext_vector_type(4))) float float4v;

static __device__ __forceinline__ float b2f(short s) {
    return __builtin_bit_cast(float, ((unsigned)(unsigned short)s) << 16);
}
// fp32 -> bf16 round-to-nearest-even (finite values only)
static __device__ __forceinline__ short f2b(float f) {
    unsigned x = __builtin_bit_cast(unsigned, f);
    unsigned r = (x + 0x7fffu + ((x >> 16) & 1u)) >> 16;
    return (short)r;
}
// async global->LDS, 16B per lane (dst must be wave-uniform base + lane*16)
static __device__ __forceinline__ void gload_lds16(const short* g, short* l) {
    __builtin_amdgcn_global_load_lds(
        (const __attribute__((address_space(1))) void*)g,
        (__attribute__((address_space(3))) void*)l, 16, 0, 0);
}
// inline-asm ds_read_b128: opaque to the waitcnt legalizer, so the compiler
// cannot insert conservative vmcnt(0) waits ordering it against global_load_lds
// staging (rule #18: caller MUST fence with lgkmcnt(0) + sched_barrier(0)
// before consuming the result).
typedef __attribute__((address_space(3))) const short* lds_cptr;
static __device__ __forceinline__ short8 ds_r128(const short* p) {
    short8 r;
    asm volatile("ds_read_b128 %0, %1" : "=v"(r) : "v"((lds_cptr)p));
    return r;
}

// ------------- prep: fp32->bf16 convert of x + all 6 weight transposes ---------
static __device__ __forceinline__ void tile_transpose(const float* __restrict__ in,
                                                      short* __restrict__ out,
                                                      int R, int C, int bx, int by,
                                                      float tile[64][65])
{
    const int tx = threadIdx.x;
    const int r0 = by * 64, c0 = bx * 64;
    const int lr = tx >> 4, lc = (tx & 15) * 4;
#pragma unroll
    for (int p = 0; p < 4; p++) {
        const float4v v = *(const float4v*)&in[(size_t)(r0 + lr + p * 16) * C + c0 + lc];
#pragma unroll
        for (int j = 0; j < 4; j++) tile[lr + p * 16][lc + j] = v[j];
    }
    __syncthreads();
    const int oc = tx >> 3, orr = (tx & 7) * 8;
#pragma unroll
    for (int p = 0; p < 2; p++) {
        const int c = oc + p * 32;
        short8 pk;
#pragma unroll
        for (int j = 0; j < 8; j++) pk[j] = f2b(tile[orr + j][c]);
        *(short8*)&out[(size_t)(c0 + c) * R + r0 + orr] = pk;
    }
}

__global__ __launch_bounds__(256) void prep_k(const float* __restrict__ x,
                                              const float* __restrict__ Wq,
                                              const float* __restrict__ Wk,
                                              const float* __restrict__ Wv,
                                              const float* __restrict__ Wp,
                                              const float* __restrict__ W1,
                                              const float* __restrict__ W2,
                                              short* __restrict__ xb,
                                              short* __restrict__ WqkvT,
                                              short* __restrict__ WpT,
                                              short* __restrict__ W1T,
                                              short* __restrict__ W2T)
{
    __shared__ float tile[64][65];
    const int b = blockIdx.x;
    if (b < 4096) {
        const size_t i = ((size_t)b * 256 + threadIdx.x) * 4;
        const float4v v = *(const float4v*)&x[i];
        short4v s;
#pragma unroll
        for (int j = 0; j < 4; j++) s[j] = f2b(v[j]);
        *(short4v*)&xb[i] = s;
    } else if (b < 5120) {
        const int lb = b - 4096;
        const int wsel = lb >> 8, t = lb & 255;
        const float* in = (wsel == 0) ? Wq : (wsel == 1) ? Wk : (wsel == 2) ? Wv : Wp;
        short* out = (wsel < 3) ? (WqkvT + ((size_t)wsel << 20)) : WpT;
        tile_transpose(in, out, 1024, 1024, t & 15, t >> 4, tile);
    } else if (b < 6144) {
        const int lb = b - 5120;
        tile_transpose(W1, W1T, 1024, 4096, lb & 63, lb >> 6, tile);
    } else {
        const int lb = b - 6144;
        tile_transpose(W2, W2T, 4096, 1024, lb & 15, lb >> 4, tile);
    }
}

// ---------------- 8-phase 256x256 GEMM: C[M,N] = X[M,K] @ Wt[N,K]^T -----------
// 512 threads / 8 waves (2M x 4N), BK=64, double-buffered 128 KiB LDS.
// LDS layout per matrix: [buf][khalf][256 rows][32 cols] bf16, rows XOR-swizzled
// (byte ^= (row&3)<<4) via pre-swizzled global_load_lds source addresses.
// Phase order per K-tile: (k0,mh0)(k0,mh1)(k1,mh1)(k1,mh0); tile t+1's four
// regions (A.k0,B.k0,A.k1,B.k1) staged one per phase into buf[(t+1)&1];
// s_waitcnt vmcnt(4) at end of phases 1 and 3 (counted, never 0 in loop).
// Fragment loads are inline-asm ds_read_b128 (see ds_r128) so the ONLY vmem
// waits in the loop are the counted ones.
// MODE 2: out = relu(v + bias[n]) bf16. MODE 4: fused QKV scatter (Q*0.125,
// K, V^T segments 4M elems apart). MODE 5: split-K over blockIdx.z, bf16
// partials at out + z*M*N (z==3 redirected to 'alt' when non-null).
template<int MODE>
__global__ __launch_bounds__(512, 2) void gemm8(const short* __restrict__ X,
                                                const short* __restrict__ Wt,
                                                short* __restrict__ out,
                                                const float* __restrict__ bias,
                                                const short* __restrict__ alt,
                                                int M, int N, int K)
{
    extern __shared__ char lds[];
    const int tid = threadIdx.x;
    const int wave = tid >> 6, lane = tid & 63;
    const int quad = lane >> 4, l16 = lane & 15;
    const int wm = (wave >> 2) * 128, wn = (wave & 3) * 64;

    int bx = blockIdx.x, by = blockIdx.y;
    {   // XCD-aware bijective swizzle (perf heuristic only)
        const int nbx = gridDim.x, nby = gridDim.y;
        if ((nby & 7) == 0) {
            const int g = by * nbx + bx;
            const int xcd = g & 7, loc = g >> 3, Y = nby >> 3;
            by = xcd * Y + (loc % Y);
            bx = loc / Y;
        }
    }
    const int m0 = by * 256, n0 = bx * 256;

    int nt = K >> 6, kb = 0;
    if (MODE == 5) { nt /= (int)gridDim.z; kb = blockIdx.z * nt; }

    // staging geometry: thread covers (row = tid>>2 [+128], 16B granule tid&3)
    const int sr = tid >> 2;
    const int ce = ((((tid & 3) << 4) ^ ((sr & 3) << 4)) >> 1);  // swizzled col (elems)
    const int sx = (l16 & 3) << 4;                               // read-side XOR (bytes)

    auto stage = [&](int t, int isB, int kh) {
        const short* src = isB ? Wt : X;
        const int rb = isB ? n0 : m0;
        const short* g = src + (size_t)(rb + sr) * K + (size_t)(kb + t) * 64 + kh * 32 + ce;
        short* d = (short*)(lds + (isB ? 65536 : 0) + ((t & 1) << 15) + (kh << 14)) + tid * 8;
        gload_lds16(g, d);
        gload_lds16(g + (size_t)128 * K, d + 4096);
    };

    float4v acc[8][4] = {};
    short8 af[4], bf[4];

    auto loadA = [&](int t, int kh, int h) {
        const char* base = lds + ((t & 1) << 15) + (kh << 14)
                         + (wm + h * 64 + l16) * 64 + ((quad << 4) ^ sx);
#pragma unroll
        for (int i = 0; i < 4; i++) af[i] = ds_r128((const short*)(base + i * 1024));
    };
    auto loadB = [&](int t, int kh) {
        const char* base = lds + 65536 + ((t & 1) << 15) + (kh << 14)
                         + (wn + l16) * 64 + ((quad << 4) ^ sx);
#pragma unroll
        for (int i = 0; i < 4; i++) bf[i] = ds_r128((const short*)(base + i * 1024));
    };
    auto mmac = [&](int h) {
#pragma unroll
        for (int mi = 0; mi < 4; mi++)
#pragma unroll
            for (int ni = 0; ni < 4; ni++)
                acc[h * 4 + mi][ni] = __builtin_amdgcn_mfma_f32_16x16x32_bf16(af[mi], bf[ni], acc[h * 4 + mi][ni], 0, 0, 0);
    };

    // prologue: stage tile 0 fully; k0 must land, k1 pair (4 loads) may fly
    stage(0, 0, 0); stage(0, 1, 0); stage(0, 0, 1); stage(0, 1, 1);
    asm volatile("s_waitcnt vmcnt(4)" ::: "memory");
    __builtin_amdgcn_s_barrier();

    for (int t = 0; t < nt - 1; ++t) {
        // phase 0: (k0, mh0); stage (t+1).A.k0
        loadA(t, 0, 0); loadB(t, 0);
        stage(t + 1, 0, 0);
        __builtin_amdgcn_s_barrier();
        asm volatile("s_waitcnt lgkmcnt(0)" ::: "memory");
        __builtin_amdgcn_sched_barrier(0);
        __builtin_amdgcn_s_setprio(1); mmac(0); __builtin_amdgcn_s_setprio(0);
        __builtin_amdgcn_s_barrier();
        // phase 1: (k0, mh1); stage (t+1).B.k0; vmcnt(4) -> tile t k1 landed
        loadA(t, 0, 1);
        stage(t + 1, 1, 0);
        __builtin_amdgcn_s_barrier();
        asm volatile("s_waitcnt lgkmcnt(0)" ::: "memory");
        __builtin_amdgcn_sched_barrier(0);
        __builtin_amdgcn_s_setprio(1); mmac(1); __builtin_amdgcn_s_setprio(0);
        asm volatile("s_waitcnt vmcnt(4)" ::: "memory");
        __builtin_amdgcn_s_barrier();
        // phase 2: (k1, mh1); stage (t+1).A.k1
        loadA(t, 1, 1); loadB(t, 1);
        stage(t + 1, 0, 1);
        __builtin_amdgcn_s_barrier();
        asm volatile("s_waitcnt lgkmcnt(0)" ::: "memory");
        __builtin_amdgcn_sched_barrier(0);
        __builtin_amdgcn_s_setprio(1); mmac(1); __builtin_amdgcn_s_setprio(0);
        __builtin_amdgcn_s_barrier();
        // phase 3: (k1, mh0); stage (t+1).B.k1; vmcnt(4) -> tile t+1 k0 landed
        loadA(t, 1, 0);
        stage(t + 1, 1, 1);
        __builtin_amdgcn_s_barrier();
        asm volatile("s_waitcnt lgkmcnt(0)" ::: "memory");
        __builtin_amdgcn_sched_barrier(0);
        __builtin_amdgcn_s_setprio(1); mmac(0); __builtin_amdgcn_s_setprio(0);
        asm volatile("s_waitcnt vmcnt(4)" ::: "memory");
        __builtin_amdgcn_s_barrier();
    }
    // epilogue tile (no staging; explicit lgkm fences before every mmac since
    // the asm ds_reads are invisible to the compiler's waitcnt insertion)
    {
        const int t = nt - 1;
        loadA(t, 0, 0); loadB(t, 0);
        asm volatile("s_waitcnt lgkmcnt(0)" ::: "memory");
        __builtin_amdgcn_sched_barrier(0);
        mmac(0);
        loadA(t, 0, 1);
        asm volatile("s_waitcnt lgkmcnt(0)" ::: "memory");
        __builtin_amdgcn_sched_barrier(0);
        mmac(1);
        asm volatile("s_waitcnt vmcnt(0)" ::: "memory");
        __builtin_amdgcn_s_barrier();
        loadA(t, 1, 1); loadB(t, 1);
        asm volatile("s_waitcnt lgkmcnt(0)" ::: "memory");
        __builtin_amdgcn_sched_barrier(0);
        mmac(1);
        loadA(t, 1, 0);
        asm volatile("s_waitcnt lgkmcnt(0)" ::: "memory");
        __builtin_amdgcn_sched_barrier(0);
        mmac(0);
    }

    short* op = out;
    if (MODE == 5) op = (blockIdx.z == 3 && alt) ? const_cast<short*>(alt)
                                                 : out + (size_t)blockIdx.z * M * N;

#pragma unroll
    for (int mf = 0; mf < 8; mf++) {
#pragma unroll
        for (int nf = 0; nf < 4; nf++) {
            const int gn = n0 + wn + nf * 16 + l16;
            const float bv = (MODE == 2) ? bias[gn] : 0.0f;
#pragma unroll
            for (int rr = 0; rr < 4; rr++) {
                const int gm = m0 + wm + mf * 16 + (quad << 2) + rr;
                float v = acc[mf][nf][rr];
                if (MODE == 4) {
                    const int s = gn >> 10;          // block-uniform
                    const int n = gn & 1023;
                    const int hh = n >> 6, d = n & 63;
                    const size_t bh16 = (size_t)((gm >> 10) * 16 + hh) << 16;
                    const size_t base = (size_t)s << 22;
                    if (s == 0)      out[base + bh16 + ((size_t)(gm & 1023) << 6) + d] = f2b(v * 0.125f);
                    else if (s == 1) out[base + bh16 + ((size_t)(gm & 1023) << 6) + d] = f2b(v);
                    else             out[base + bh16 + ((size_t)d << 10) + (gm & 1023)] = f2b(v);
                } else if (MODE == 2) {
                    v = fmaxf(v + bv, 0.0f);
                    out[(size_t)gm * N + gn] = f2b(v);
                } else {   // MODE 5
                    op[(size_t)gm * N + gn] = f2b(v);
                }
            }
        }
    }
}

// ---------------- attention v4: LDS-staged, no-rescale softmax -----------------
__global__ __launch_bounds__(256) void attn_k(const short* __restrict__ Qb,
                                              const short* __restrict__ Kb,
                                              const short* __restrict__ Vt,
                                              const int* __restrict__ mask,
                                              short* __restrict__ heads)
{
    __shared__ short Kl[2][64 * 32];
    __shared__ short Vl[2][64 * 32];
    __shared__ short P[4][16 * 72];
    const int bh = blockIdx.x, qb = blockIdx.y;
    const int b = bh >> 4, h = bh & 15;
    const int tid = threadIdx.x, wave = tid >> 6, lane = tid & 63;
    const int quad = lane >> 4, l16 = lane & 15;
    const int qbase = qb * 64 + wave * 16;
    const short* Qp = Qb + ((size_t)bh << 16) + (size_t)qbase * 64;
    const short* Kp = Kb + ((size_t)bh << 16);
    const short* Vp = Vt + ((size_t)bh << 16);
    const int* mp = mask + (b << 10);

    const short8 bq0 = *(const short8*)&Qp[l16 * 64 + quad * 8];
    const short8 bq1 = *(const short8*)&Qp[l16 * 64 + 32 + quad * 8];

    float rs = 0.0f;
    float4v o[4] = {};
    short* myP = &P[wave][0];

    const int srow = tid >> 2, sc8 = (tid & 3) * 8;

    for (int kc = 0; kc < 1024; kc += 64) {
        gload_lds16(Kp + (size_t)(kc + srow) * 64 + sc8,      &Kl[0][tid * 8]);
        gload_lds16(Kp + (size_t)(kc + srow) * 64 + 32 + sc8, &Kl[1][tid * 8]);
        gload_lds16(Vp + (size_t)srow * 1024 + kc + sc8,      &Vl[0][tid * 8]);
        gload_lds16(Vp + (size_t)srow * 1024 + kc + 32 + sc8, &Vl[1][tid * 8]);
        __syncthreads();

        float4v s[4];
#pragma unroll
        for (int kt = 0; kt < 4; kt++) {
            s[kt] = (float4v){};
            const short8 ka = *(const short8*)&Kl[0][(kt * 16 + l16) * 32 + quad * 8];
            s[kt] = __builtin_amdgcn_mfma_f32_16x16x32_bf16(ka, bq0, s[kt], 0, 0, 0);
            const short8 kb = *(const short8*)&Kl[1][(kt * 16 + l16) * 32 + quad * 8];
            s[kt] = __builtin_amdgcn_mfma_f32_16x16x32_bf16(kb, bq1, s[kt], 0, 0, 0);
        }
#pragma unroll
        for (int kt = 0; kt < 4; kt++) {
            const int4 mv = *(const int4*)&mp[kc + kt * 16 + quad * 4];
            float p0 = mv.x ? __expf(fminf(s[kt][0], 30.f)) : 0.f;
            float p1 = mv.y ? __expf(fminf(s[kt][1], 30.f)) : 0.f;
            float p2 = mv.z ? __expf(fminf(s[kt][2], 30.f)) : 0.f;
            float p3 = mv.w ? __expf(fminf(s[kt][3], 30.f)) : 0.f;
            rs += (p0 + p1) + (p2 + p3);
            short4v w;
            w[0] = f2b(p0); w[1] = f2b(p1); w[2] = f2b(p2); w[3] = f2b(p3);
            *(short4v*)&myP[l16 * 72 + kt * 16 + quad * 4] = w;
        }
        const short8 bp0 = *(const short8*)&myP[l16 * 72 + quad * 8];
        const short8 bp1 = *(const short8*)&myP[l16 * 72 + 32 + quad * 8];
#pragma unroll
        for (int dt = 0; dt < 4; dt++) {
            const short8 va = *(const short8*)&Vl[0][(dt * 16 + l16) * 32 + quad * 8];
            o[dt] = __builtin_amdgcn_mfma_f32_16x16x32_bf16(va, bp0, o[dt], 0, 0, 0);
            const short8 vb = *(const short8*)&Vl[1][(dt * 16 + l16) * 32 + quad * 8];
            o[dt] = __builtin_amdgcn_mfma_f32_16x16x32_bf16(vb, bp1, o[dt], 0, 0, 0);
        }
        __syncthreads();
    }

    rs += __shfl_xor(rs, 16);
    rs += __shfl_xor(rs, 32);
    const float inv = 1.0f / fmaxf(rs, 1e-20f);
    const int gq = qbase + l16;
#pragma unroll
    for (int dt = 0; dt < 4; dt++) {
        short4v w;
#pragma unroll
        for (int r = 0; r < 4; r++) w[r] = f2b(o[dt][r] * inv);
        *(short4v*)&heads[((size_t)(b * 1024 + gq) << 10) + h * 64 + dt * 16 + quad * 4] = w;
    }
}

// ------- fused split-K(4) reduce + LayerNorm: y = p0+p1+p2+p3+bias+res --------
template<bool F32OUT>
__global__ __launch_bounds__(256) void red_ln_k(const short* __restrict__ p0,
                                                const short* __restrict__ p1,
                                                const short* __restrict__ p2,
                                                const short* __restrict__ p3,
                                                const float* __restrict__ bias,
                                                const short* __restrict__ res,
                                                const float* __restrict__ g,
                                                const float* __restrict__ be,
                                                short* __restrict__ outb,
                                                float* __restrict__ outf)
{
    __shared__ float red[8];
    const int row = blockIdx.x, tid = threadIdx.x;
    const size_t base = ((size_t)row << 10) + tid * 4;
    const short4v a = *(const short4v*)&p0[base];
    const short4v b = *(const short4v*)&p1[base];
    const short4v c = *(const short4v*)&p2[base];
    const short4v d = *(const short4v*)&p3[base];
    const short4v e = *(const short4v*)&res[base];
    const float4v bv = *(const float4v*)&bias[tid * 4];
    float v[4];
#pragma unroll
    for (int i = 0; i < 4; i++)
        v[i] = (b2f(a[i]) + b2f(b[i])) + (b2f(c[i]) + b2f(d[i])) + bv[i] + b2f(e[i]);
    float s = v[0] + v[1] + v[2] + v[3];
#pragma unroll
    for (int off = 32; off; off >>= 1) s += __shfl_xor(s, off);
    if ((tid & 63) == 0) red[tid >> 6] = s;
    __syncthreads();
    const float mu = (red[0] + red[1] + red[2] + red[3]) * (1.0f / 1024.0f);
    float vs = 0.f;
#pragma unroll
    for (int i = 0; i < 4; i++) { const float dd = v[i] - mu; vs += dd * dd; }
#pragma unroll
    for (int off = 32; off; off >>= 1) vs += __shfl_xor(vs, off);
    if ((tid & 63) == 0) red[4 + (tid >> 6)] = vs;
    __syncthreads();
    const float rstd = rsqrtf((red[4] + red[5] + red[6] + red[7]) * (1.0f / 1024.0f) + 1e-5f);
    const float4v gv = *(const float4v*)&g[tid * 4];
    const float4v bev = *(const float4v*)&be[tid * 4];
    if (F32OUT) {
        float4v w;
#pragma unroll
        for (int i = 0; i < 4; i++) w[i] = (v[i] - mu) * rstd * gv[i] + bev[i];
        *(float4v*)&outf[base] = w;
    } else {
        short4v w;
#pragma unroll
        for (int i = 0; i < 4; i++) w[i] = f2b((v[i] - mu) * rstd * gv[i] + bev[i]);
        *(short4v*)&outb[base] = w;
    }
}

extern "C" void kernel_launch(void* const* d_in, const int* in_sizes, int n_in,
                              void* d_out, int out_size, void* d_ws, size_t ws_size,
                              hipStream_t stream)
{
    const float* x   = (const float*)d_in[0];
    const int*   mk  = (const int*)d_in[1];
    const float* Wq  = (const float*)d_in[2];
    const float* Wk  = (const float*)d_in[3];
    const float* Wv  = (const float*)d_in[4];
    const float* Wp  = (const float*)d_in[5];
    const float* bp  = (const float*)d_in[6];
    const float* W1  = (const float*)d_in[7];
    const float* b1  = (const float*)d_in[8];
    const float* W2  = (const float*)d_in[9];
    const float* b2  = (const float*)d_in[10];
    const float* g1  = (const float*)d_in[11];
    const float* be1 = (const float*)d_in[12];
    const float* g2  = (const float*)d_in[13];
    const float* be2 = (const float*)d_in[14];
    float* out = (float*)d_out;

    char* ws = (char*)d_ws;
    const size_t MB = (size_t)1 << 20;
    // liveness-packed 80 MB workspace:
    short* xb     = (short*)(ws + 0 * MB);   // 8 MB   (steps 0->4, residual 1)
    short* WqkvT  = (short*)(ws + 8 * MB);   // 6 MB   (0->1)
    short* WpT    = (short*)(ws + 14 * MB);  // 2 MB   (0->3)
    short* W1T    = (short*)(ws + 16 * MB);  // 8 MB   (0->5)
    short* partP  = (short*)(ws + 24 * MB);  // 32 MB  (3->4) proj partials, 4 slices
    short* u      = (short*)(ws + 24 * MB);  // 32 MB  (5->6) FF1 out (over partP)
    short* Qb     = (short*)(ws + 32 * MB);  // 8+8+8  (1->2) Q,K,V segments
    short* hd     = (short*)(ws + 56 * MB);  // 8 MB   (2->3) heads
    short* hbuf   = (short*)(ws + 64 * MB);  // 8 MB   (4->7) LN1 out (residual 2)
    short* W2T    = (short*)(ws + 72 * MB);  // 8 MB   (0->6)
    short* partF  = (short*)(ws + 0 * MB);   // slices 0,1,2 @ 0,8,16 MB (6->7)
    short* partF3 = (short*)(ws + 56 * MB);  // slice 3 over dead hd

    // opt-in to 128 KiB dynamic LDS for the 8-phase GEMM (host-side, capture-safe)
    hipFuncSetAttribute(reinterpret_cast<const void*>(gemm8<4>),
                        hipFuncAttributeMaxDynamicSharedMemorySize, 131072);
    hipFuncSetAttribute(reinterpret_cast<const void*>(gemm8<2>),
                        hipFuncAttributeMaxDynamicSharedMemorySize, 131072);
    hipFuncSetAttribute(reinterpret_cast<const void*>(gemm8<5>),
                        hipFuncAttributeMaxDynamicSharedMemorySize, 131072);

    const dim3 blk(256), blk8(512);

    // 0) prep: cvt(x) + 6 weight transposes in one launch
    prep_k<<<dim3(7168), blk, 0, stream>>>(x, Wq, Wk, Wv, Wp, W1, W2,
                                           xb, WqkvT, WpT, W1T, W2T);

    // 1) fused QKV: M=4096, N=3072, K=1024 -> 192 blocks (256^2 tiles)
    gemm8<4><<<dim3(12, 16), blk8, 131072, stream>>>(xb, WqkvT, Qb, nullptr, nullptr, 4096, 3072, 1024);

    // 2) attention -> heads
    attn_k<<<dim3(64, 16), blk, 0, stream>>>(Qb, Qb + (4u << 20), Qb + (8u << 20), mk, hd);

    // 3) out-proj split-K=4: 64 tiles x 4 slices = 256 blocks, K=256 each
    gemm8<5><<<dim3(4, 16, 4), blk8, 131072, stream>>>(hd, WpT, partP, nullptr, nullptr, 4096, 1024, 1024);

    // 4) reduce(4) + bias + residual(xb) + LN1 -> hbuf
    red_ln_k<false><<<dim3(4096), blk, 0, stream>>>(partP, partP + (4u << 20), partP + (8u << 20), partP + (12u << 20),
                                                    bp, xb, g1, be1, hbuf, nullptr);

    // 5) FF1 + bias + relu: 256 blocks (1/CU)
    gemm8<2><<<dim3(16, 16), blk8, 131072, stream>>>(hbuf, W1T, u, b1, nullptr, 4096, 4096, 1024);

    // 6) FF2 split-K=4: 64 tiles x 4 = 256 blocks, K=1024 each; slice 3 -> partF3
    gemm8<5><<<dim3(4, 16, 4), blk8, 131072, stream>>>(u, W2T, partF, nullptr, partF3, 4096, 1024, 4096);

    // 7) reduce(4) + bias + residual(hbuf) + LN2 -> out (fp32)
    red_ln_k<true><<<dim3(4096), blk, 0, stream>>>(partF, partF + (4u << 20), partF + (8u << 20), partF3,
                                                   b2, hbuf, g2, be2, nullptr, out);
}